// Round 1
// 2500.857 us; speedup vs baseline: 1.0392x; 1.0392x over previous
//
#include <hip/hip_runtime.h>
#include <math.h>

#define BB 2
#define SDOC 2048
#define SSUM 1024
#define HD 768
#define NHEAD 12
#define DHEAD 64
#define FFD 3072
#define NLAYER 6
#define PD 256
#define NSPAN 32
#define WINSZ 256
#define QKVN 2304   // fused QKV output width
#define MTOT 6144   // merged rows: BB*SDOC + BB*SSUM
#define KSPLIT 16   // split-K factor for the tiny projection-head GEMMs

typedef short s16x8 __attribute__((ext_vector_type(8)));
typedef float f32x4 __attribute__((ext_vector_type(4)));

#define LDS_PTR(p) ((__attribute__((address_space(3))) void*)(p))
#define GLB_PTR(p) ((const __attribute__((address_space(1))) void*)(p))

// ---------------- bf16 helpers (RNE) ----------------
__device__ __forceinline__ unsigned short f2bf(float f) {
  unsigned int u = __builtin_bit_cast(unsigned int, f);
  unsigned int r = (u + 0x7fffu + ((u >> 16) & 1u)) >> 16;
  return (unsigned short)r;
}
__device__ __forceinline__ float bf2f(unsigned short h) {
  unsigned int u = ((unsigned int)h) << 16;
  return __builtin_bit_cast(float, u);
}

// fast GELU (tanh form via exp). max abs err ~2e-4 — far below bf16 noise.
__device__ __forceinline__ float gelu_f(float x) {
  float t = x * (0.7978845608f + 0.0356774081f * x * x);
  float e = __expf(2.f * t);
  float th = 1.f - 2.f / (e + 1.f);
  return 0.5f * x * (1.f + th);
}

// ---------------- block reductions (blockDim == 256) ----------------
__device__ __forceinline__ float block_reduce_sum(float v) {
  __shared__ float sbuf[256];
  sbuf[threadIdx.x] = v;
  __syncthreads();
  for (int i = 128; i > 0; i >>= 1) {
    if ((int)threadIdx.x < i) sbuf[threadIdx.x] += sbuf[threadIdx.x + i];
    __syncthreads();
  }
  float r = sbuf[0];
  __syncthreads();
  return r;
}

__device__ __forceinline__ float block_reduce_max(float v) {
  __shared__ float mbuf[256];
  mbuf[threadIdx.x] = v;
  __syncthreads();
  for (int i = 128; i > 0; i >>= 1) {
    if ((int)threadIdx.x < i) mbuf[threadIdx.x] = fmaxf(mbuf[threadIdx.x], mbuf[threadIdx.x + i]);
    __syncthreads();
  }
  float r = mbuf[0];
  __syncthreads();
  return r;
}

// ---------------- embedding + LayerNorm + bf16 ----------------
__global__ __launch_bounds__(256) void embed_ln_kernel(
    const int* __restrict__ ids, const float* __restrict__ we, const float* __restrict__ pe,
    const float* __restrict__ g, const float* __restrict__ bt, float* __restrict__ xout,
    unsigned short* __restrict__ xb, int S) {
  int row = blockIdx.x;
  int s = row % S;
  int id = ids[row];
  int tid = threadIdx.x;
  float vals[3];
  float sum = 0.f;
#pragma unroll
  for (int i = 0; i < 3; i++) {
    int h = tid + i * 256;
    float t = we[(size_t)id * HD + h] + pe[(size_t)s * HD + h];
    vals[i] = t;
    sum += t;
  }
  float mean = block_reduce_sum(sum) * (1.f / HD);
  float vs = 0.f;
#pragma unroll
  for (int i = 0; i < 3; i++) { float d = vals[i] - mean; vs += d * d; }
  float var = block_reduce_sum(vs) * (1.f / HD);
  float inv = rsqrtf(var + 1e-5f);
#pragma unroll
  for (int i = 0; i < 3; i++) {
    int h = tid + i * 256;
    float v = (vals[i] - mean) * inv * g[h] + bt[h];
    size_t off = (size_t)row * HD + h;
    xout[off] = v;
    xb[off] = f2bf(v);
  }
}

// ---------------- LayerNorm (+optional residual, +optional bf16 out) ----------------
__global__ __launch_bounds__(256) void ln_kernel(
    const float* __restrict__ a, const float* __restrict__ res,
    const float* __restrict__ g, const float* __restrict__ bt, float* __restrict__ out,
    unsigned short* __restrict__ ob) {
  int row = blockIdx.x;
  int tid = threadIdx.x;
  const float* ar = a + (size_t)row * HD;
  const float* rr = res ? res + (size_t)row * HD : nullptr;
  float vals[3];
  float sum = 0.f;
#pragma unroll
  for (int i = 0; i < 3; i++) {
    int h = tid + i * 256;
    float t = ar[h] + (rr ? rr[h] : 0.f);
    vals[i] = t;
    sum += t;
  }
  float mean = block_reduce_sum(sum) * (1.f / HD);
  float vs = 0.f;
#pragma unroll
  for (int i = 0; i < 3; i++) { float d = vals[i] - mean; vs += d * d; }
  float var = block_reduce_sum(vs) * (1.f / HD);
  float inv = rsqrtf(var + 1e-5f);
#pragma unroll
  for (int i = 0; i < 3; i++) {
    int h = tid + i * 256;
    float v = (vals[i] - mean) * inv * g[h] + bt[h];
    size_t off = (size_t)row * HD + h;
    out[off] = v;
    if (ob) ob[off] = f2bf(v);
  }
}

// ---------------- per-layer weight transpose + bf16 cast ----------------
__global__ __launch_bounds__(256) void tc_cast_kernel(
    const float* __restrict__ Wq, const float* __restrict__ Wk, const float* __restrict__ Wv,
    const float* __restrict__ Wo, const float* __restrict__ Wf1, const float* __restrict__ Wf2,
    unsigned short* __restrict__ ob) {
  __shared__ float tile[32][33];
  int z = blockIdx.z;
  const float* W;
  int Kd, Nd;
  size_t off;
  switch (z) {
    case 0: W = Wq;  Kd = HD;  Nd = HD;  off = 0;        break;
    case 1: W = Wk;  Kd = HD;  Nd = HD;  off = 589824;   break;
    case 2: W = Wv;  Kd = HD;  Nd = HD;  off = 1179648;  break;
    case 3: W = Wo;  Kd = HD;  Nd = HD;  off = 1769472;  break;
    case 4: W = Wf1; Kd = HD;  Nd = FFD; off = 2359296;  break;
    default: W = Wf2; Kd = FFD; Nd = HD; off = 4718592;  break;
  }
  int tiles_n = Nd >> 5, tiles_k = Kd >> 5;
  int t = blockIdx.x;
  if (t >= tiles_n * tiles_k) return;
  int tn = t % tiles_n, tk = t / tiles_n;
  int n0 = tn * 32, k0 = tk * 32;
  int tid = threadIdx.x;
  int c = tid & 31, r0 = tid >> 5;
#pragma unroll
  for (int j = 0; j < 4; j++) {
    int r = r0 + j * 8;
    tile[r][c] = W[(size_t)(k0 + r) * Nd + n0 + c];
  }
  __syncthreads();
#pragma unroll
  for (int j = 0; j < 4; j++) {
    int r = r0 + j * 8;  // r = local n, c = local k
    ob[off + (size_t)(n0 + r) * Kd + k0 + c] = f2bf(tile[c][r]);
  }
}

// ---------------- bf16 MFMA GEMM, double-buffered LDS, templated N-tile ----------------
// C(M,N) = A(M,K)bf16 @ B^T, B stored (N,K) row-major bf16. Block tile 128 x TN.
// bias segments: col c -> bias[c/seg] ptr b0/b1/b2, offset c%seg.
// act=1: fast GELU. Output fp32 C (if non-null) and/or bf16 Oh (if non-null).
template <int TN>
__global__ __launch_bounds__(256) void gemm_mfma_t(
    const unsigned short* __restrict__ A, const unsigned short* __restrict__ B,
    const float* __restrict__ b0, const float* __restrict__ b1, const float* __restrict__ b2,
    int seg, float* __restrict__ C, unsigned short* __restrict__ Oh,
    int M, int N, int K, int act) {
  constexpr int JT = TN / 32;  // n-fragments per wave
  __shared__ __align__(16) unsigned short sA[2][128 * 32];
  __shared__ __align__(16) unsigned short sB[2][TN * 32];
  int tid = threadIdx.x;
  int bm = blockIdx.y * 128, bn = blockIdx.x * TN;
  int wave = tid >> 6, lane = tid & 63;
  int quad = lane >> 4, l16 = lane & 15;
  int wm = (wave >> 1) * 64, wn = (wave & 1) * (TN / 2);

  f32x4 zero = {0.f, 0.f, 0.f, 0.f};
  f32x4 acc[4][JT];
#pragma unroll
  for (int i = 0; i < 4; i++)
#pragma unroll
    for (int j = 0; j < JT; j++) acc[i][j] = zero;

  int e0 = tid * 8;
  int row0 = e0 >> 5;
  int kk0 = e0 & 31;

  auto issue = [&](int kb, int buf) {
    int k0 = kb * 32;
#pragma unroll
    for (int r = 0; r < 2; r++) {
      int row = row0 + r * 64;
      int le = (r * 256 + tid) * 8;
      size_t ga = (size_t)(bm + row) * K + k0 + kk0;
      __builtin_amdgcn_global_load_lds(GLB_PTR(A + ga), LDS_PTR(&sA[buf][le]), 16, 0, 0);
    }
#pragma unroll
    for (int r = 0; r < TN / 64; r++) {
      int row = row0 + r * 64;
      int le = (r * 256 + tid) * 8;
      size_t gb = (size_t)(bn + row) * K + k0 + kk0;
      __builtin_amdgcn_global_load_lds(GLB_PTR(B + gb), LDS_PTR(&sB[buf][le]), 16, 0, 0);
    }
  };

  int nk = K >> 5;
  issue(0, 0);
  for (int kb = 0; kb < nk; kb++) {
    __syncthreads();  // drains loads for buf kb&1; ensures prior reads of other buf done
    if (kb + 1 < nk) issue(kb + 1, (kb + 1) & 1);
    int buf = kb & 1;
    s16x8 af[4], bf[JT];
#pragma unroll
    for (int i = 0; i < 4; i++)
      af[i] = *(const s16x8*)&sA[buf][(wm + i * 16 + l16) * 32 + quad * 8];
#pragma unroll
    for (int j = 0; j < JT; j++)
      bf[j] = *(const s16x8*)&sB[buf][(wn + j * 16 + l16) * 32 + quad * 8];
#pragma unroll
    for (int i = 0; i < 4; i++)
#pragma unroll
      for (int j = 0; j < JT; j++)
        acc[i][j] = __builtin_amdgcn_mfma_f32_16x16x32_bf16(af[i], bf[j], acc[i][j], 0, 0, 0);
  }

#pragma unroll
  for (int j = 0; j < JT; j++) {
    int col = bn + wn + j * 16 + l16;
    int bidx = col / seg;
    int boff = col - bidx * seg;
    const float* bp = bidx == 0 ? b0 : (bidx == 1 ? b1 : b2);
    float bv = bp[boff];
#pragma unroll
    for (int i = 0; i < 4; i++) {
#pragma unroll
      for (int r = 0; r < 4; r++) {
        int rowg = bm + wm + i * 16 + quad * 4 + r;
        float v = acc[i][j][r] + bv;
        if (act == 1) v = gelu_f(v);
        size_t off = (size_t)rowg * N + col;
        if (C) C[off] = v;
        if (Oh) Oh[off] = f2bf(v);
      }
    }
  }
}

// ---------------- projection-head GEMM: split-K partials + fused reduce ----------------
// partial: part[(ks*M + m)*N + n] = sum over k in [ks*K/KSPLIT, (ks+1)*K/KSPLIT)
// grid (N/256, M, KSPLIT), 256 threads. N multiple of 256, K multiple of 4*KSPLIT.
__global__ __launch_bounds__(256) void gemm_ps_kernel(
    const float* __restrict__ A, const float* __restrict__ W,
    float* __restrict__ part, int N, int K) {
  int n = blockIdx.x * 256 + threadIdx.x;
  int m = blockIdx.y;
  int M = gridDim.y;
  int ks = blockIdx.z;
  int kc = K / KSPLIT;
  int k0 = ks * kc;
  const float* ar = A + (size_t)m * K + k0;
  const float* wr = W + (size_t)k0 * N + n;
  float a0 = 0.f, a1 = 0.f, a2 = 0.f, a3 = 0.f;
  for (int k = 0; k < kc; k += 4) {
    a0 += ar[k]     * wr[(size_t)k * N];
    a1 += ar[k + 1] * wr[(size_t)(k + 1) * N];
    a2 += ar[k + 2] * wr[(size_t)(k + 2) * N];
    a3 += ar[k + 3] * wr[(size_t)(k + 3) * N];
  }
  part[((size_t)ks * M + m) * N + n] = (a0 + a1) + (a2 + a3);
}

// grid (N/256, M), 256 threads: sum KSPLIT partials + bias (+GELU)
__global__ __launch_bounds__(256) void gemm_reduce_kernel(
    const float* __restrict__ part, const float* __restrict__ bias,
    float* __restrict__ C, int N, int act) {
  int n = blockIdx.x * 256 + threadIdx.x;
  int m = blockIdx.y;
  int M = gridDim.y;
  float s = 0.f;
#pragma unroll
  for (int ks = 0; ks < KSPLIT; ks++) s += part[((size_t)ks * M + m) * N + n];
  s += bias[n];
  if (act == 1) s = gelu_f(s);
  C[(size_t)m * N + n] = s;
}

// ---------------- MFMA sliding-window attention ----------------
#define AQT 64
__global__ __launch_bounds__(256) void attn_mfma(
    const unsigned short* __restrict__ qkv, const int* __restrict__ amask,
    unsigned short* __restrict__ Oh, int S) {
  __shared__ unsigned short Vs[64][72];      // V^T: [d][key], +8 pad
  __shared__ unsigned short Ps[4][16][72];   // per-wave P (query, key), +8 pad
  int b = blockIdx.z, hd = blockIdx.y;
  int p0 = blockIdx.x * AQT;
  int tid = threadIdx.x;
  int wave = tid >> 6, lane = tid & 63;
  int quad = lane >> 4, l16 = lane & 15;
  int kstart = p0 - WINSZ;
  const unsigned short* base = qkv + (size_t)(b * S) * QKVN + hd * DHEAD;

  s16x8 aq[2];
  {
    const unsigned short* qrow = base + (size_t)(p0 + wave * 16 + l16) * QKVN;
    aq[0] = *(const s16x8*)(qrow + quad * 8);
    aq[1] = *(const s16x8*)(qrow + 32 + quad * 8);
  }
  f32x4 o[4];
  f32x4 zero = {0.f, 0.f, 0.f, 0.f};
#pragma unroll
  for (int i = 0; i < 4; i++) o[i] = zero;
  float mi[4] = {-1e30f, -1e30f, -1e30f, -1e30f};
  float li[4] = {0.f, 0.f, 0.f, 0.f};

  for (int t = 0; t < 9; t++) {
    __syncthreads();
    {
      int key = tid & 63, d0 = (tid >> 6) * 16;
      int kp = kstart + t * 64 + key;
      if (kp >= 0 && kp < S) {
        const unsigned short* vrow = base + (size_t)kp * QKVN + 2 * HD + d0;
        s16x8 v0 = *(const s16x8*)(vrow);
        s16x8 v1 = *(const s16x8*)(vrow + 8);
#pragma unroll
        for (int j = 0; j < 8; j++) Vs[d0 + j][key] = (unsigned short)v0[j];
#pragma unroll
        for (int j = 0; j < 8; j++) Vs[d0 + 8 + j][key] = (unsigned short)v1[j];
      } else {
#pragma unroll
        for (int j = 0; j < 16; j++) Vs[d0 + j][key] = 0;
      }
    }
    __syncthreads();

    f32x4 sc[4];
#pragma unroll
    for (int nt = 0; nt < 4; nt++) {
      int kr = kstart + t * 64 + nt * 16 + l16;
      s16x8 bk0 = {0, 0, 0, 0, 0, 0, 0, 0}, bk1 = bk0;
      if (kr >= 0 && kr < S) {
        const unsigned short* krow = base + (size_t)kr * QKVN + HD;
        bk0 = *(const s16x8*)(krow + quad * 8);
        bk1 = *(const s16x8*)(krow + 32 + quad * 8);
      }
      sc[nt] = __builtin_amdgcn_mfma_f32_16x16x32_bf16(aq[0], bk0, zero, 0, 0, 0);
      sc[nt] = __builtin_amdgcn_mfma_f32_16x16x32_bf16(aq[1], bk1, sc[nt], 0, 0, 0);
    }

    float s_val[4][4];
    float tm[4] = {-1e30f, -1e30f, -1e30f, -1e30f};
#pragma unroll
    for (int nt = 0; nt < 4; nt++) {
      int j = t * 64 + nt * 16 + l16;
      int kp = kstart + j;
      int am = (kp >= 0 && kp < S) ? amask[b * S + kp] : 0;
#pragma unroll
      for (int r = 0; r < 4; r++) {
        int ql = wave * 16 + quad * 4 + r;
        bool valid = (am != 0) && (j >= ql) && (j <= ql + 512);
        float v = valid ? sc[nt][r] * 0.125f : -1e9f;
        s_val[nt][r] = v;
        tm[r] = fmaxf(tm[r], v);
      }
    }
#pragma unroll
    for (int m = 1; m < 16; m <<= 1)
#pragma unroll
      for (int r = 0; r < 4; r++) tm[r] = fmaxf(tm[r], __shfl_xor(tm[r], m, 16));

    float alpha[4], rs[4];
#pragma unroll
    for (int r = 0; r < 4; r++) {
      float mn = fmaxf(mi[r], tm[r]);
      alpha[r] = __expf(mi[r] - mn);
      mi[r] = mn;
      rs[r] = 0.f;
    }
#pragma unroll
    for (int nt = 0; nt < 4; nt++)
#pragma unroll
      for (int r = 0; r < 4; r++) {
        float p = __expf(s_val[nt][r] - mi[r]);
        rs[r] += p;
        Ps[wave][quad * 4 + r][nt * 16 + l16] = f2bf(p);
      }
#pragma unroll
    for (int m = 1; m < 16; m <<= 1)
#pragma unroll
      for (int r = 0; r < 4; r++) rs[r] += __shfl_xor(rs[r], m, 16);
#pragma unroll
    for (int r = 0; r < 4; r++) li[r] = li[r] * alpha[r] + rs[r];
#pragma unroll
    for (int dn = 0; dn < 4; dn++)
#pragma unroll
      for (int r = 0; r < 4; r++) o[dn][r] *= alpha[r];

#pragma unroll
    for (int ks = 0; ks < 2; ks++) {
      s16x8 ap = *(const s16x8*)&Ps[wave][l16][ks * 32 + quad * 8];
#pragma unroll
      for (int dn = 0; dn < 4; dn++) {
        s16x8 bv = *(const s16x8*)&Vs[dn * 16 + l16][ks * 32 + quad * 8];
        o[dn] = __builtin_amdgcn_mfma_f32_16x16x32_bf16(ap, bv, o[dn], 0, 0, 0);
      }
    }
  }

#pragma unroll
  for (int r = 0; r < 4; r++) {
    float inv = 1.f / li[r];
    int rowg = b * S + p0 + wave * 16 + quad * 4 + r;
#pragma unroll
    for (int dn = 0; dn < 4; dn++) {
      Oh[(size_t)rowg * HD + hd * DHEAD + dn * 16 + l16] = f2bf(o[dn][r] * inv);
    }
  }
}

// ---------------- pooling path ----------------
__global__ __launch_bounds__(256) void dots_kernel(
    const float* __restrict__ x, const float* __restrict__ pw, float* __restrict__ dots) {
  int row = blockIdx.x * 4 + (threadIdx.x >> 6);
  int lane = threadIdx.x & 63;
  const float* r = x + (size_t)row * HD;
  float s = 0.f;
  for (int i = lane; i < HD; i += 64) s += r[i] * pw[i];
#pragma unroll
  for (int m = 32; m > 0; m >>= 1) s += __shfl_xor(s, m, 64);
  if (lane == 0) dots[row] = fminf(fmaxf(s, -100.f), 100.f);
}

// merged masked softmax: blocks 0..31 = og spans (doc), 32..63 = llm spans (sum)
__global__ __launch_bounds__(256) void span_softmax_kernel(
    const float* __restrict__ dots, const int* __restrict__ og_spans,
    const int* __restrict__ llm_spans, const int* __restrict__ sidx,
    float* __restrict__ probs) {
  int ns = blockIdx.x;
  int pass = ns >> 5;
  int sp = ns & 31;
  int S = pass ? SSUM : SDOC;
  const int* spans = pass ? llm_spans : og_spans;
  int rowbase = pass ? BB * SDOC : 0;
  int bi = sidx[sp];
  const float* dr = dots + rowbase + bi * S;
  int tid = threadIdx.x;
  float mx = -1e30f;
  for (int s = tid; s < S; s += 256) {
    float v = (spans[sp * S + s] == 1) ? dr[s] : -1e9f;
    mx = fmaxf(mx, v);
  }
  mx = block_reduce_max(mx);
  float sum = 0.f;
  for (int s = tid; s < S; s += 256) {
    float v = (spans[sp * S + s] == 1) ? dr[s] : -1e9f;
    float e = __expf(v - mx);
    probs[ns * SDOC + s] = e;
    sum += e;
  }
  sum = block_reduce_sum(sum);
  float inv = 1.f / sum;
  for (int s = tid; s < S; s += 256) probs[ns * SDOC + s] *= inv;
}

// pooled[ns][h] += sum_{s in chunk} probs[ns][s] * seq[bi][s][h]
__global__ __launch_bounds__(256) void wsum_kernel(
    const float* __restrict__ seq, const float* __restrict__ probs,
    const int* __restrict__ sidx, float* __restrict__ pooled, int S, int ns0) {
  __shared__ float ps[256];
  int sp = blockIdx.y;
  int ns = ns0 + sp;
  int s0 = blockIdx.x * 256;
  int bi = sidx[sp];
  int tid = threadIdx.x;
  ps[tid] = probs[ns * SDOC + s0 + tid];
  __syncthreads();
  const float* xb = seq + ((size_t)bi * S + s0) * HD;
  float a0 = 0.f, a1 = 0.f, a2 = 0.f;
  for (int s = 0; s < 256; s++) {
    float p = ps[s];
    const float* row = xb + (size_t)s * HD;
    a0 += p * row[tid];
    a1 += p * row[tid + 256];
    a2 += p * row[tid + 512];
  }
  atomicAdd(&pooled[ns * HD + tid], a0);
  atomicAdd(&pooled[ns * HD + tid + 256], a1);
  atomicAdd(&pooled[ns * HD + tid + 512], a2);
}

// ---------------- final L2 normalize ----------------
__global__ __launch_bounds__(256) void norm_out_kernel(
    const float* __restrict__ proj, float* __restrict__ out) {
  int ns = blockIdx.x;
  float v = proj[ns * PD + threadIdx.x];
  float ss = block_reduce_sum(v * v);
  float n = fmaxf(sqrtf(ss), 1e-12f);
  out[ns * PD + threadIdx.x] = v / n;
}

// ---------------- host side ----------------
static void launch_gemm128(const unsigned short* A, const unsigned short* B,
                           const float* b0, const float* b1, const float* b2, int seg,
                           float* C, unsigned short* Oh, int M, int N, int K, int act,
                           hipStream_t stream) {
  dim3 grid(N / 128, M / 128);
  gemm_mfma_t<128><<<grid, 256, 0, stream>>>(A, B, b0, b1, b2, seg, C, Oh, M, N, K, act);
}

// weight segment offsets in the per-layer transposed cache (elements)
#define WOFF_QKV 0
#define WOFF_O   1769472
#define WOFF_F1  2359296
#define WOFF_F2  4718592

extern "C" void kernel_launch(void* const* d_in, const int* in_sizes, int n_in,
                              void* d_out, int out_size, void* d_ws, size_t ws_size,
                              hipStream_t stream) {
  const int* doc_ids   = (const int*)d_in[0];
  const int* doc_am    = (const int*)d_in[1];
  const int* sum_ids   = (const int*)d_in[2];
  const int* sum_am    = (const int*)d_in[3];
  const int* og_spans  = (const int*)d_in[4];
  const int* llm_spans = (const int*)d_in[5];
  const int* sidx      = (const int*)d_in[6];
  const float* word_emb = (const float*)d_in[7];
  const float* pos_emb  = (const float*)d_in[8];
  const float* emb_g = (const float*)d_in[9];
  const float* emb_b = (const float*)d_in[10];
  const float* Wq = (const float*)d_in[11];
  const float* bq = (const float*)d_in[12];
  const float* Wk = (const float*)d_in[13];
  const float* bk = (const float*)d_in[14];
  const float* Wv = (const float*)d_in[15];
  const float* bv = (const float*)d_in[16];
  const float* Wo = (const float*)d_in[17];
  const float* bo = (const float*)d_in[18];
  const float* lnag = (const float*)d_in[19];
  const float* lnab = (const float*)d_in[20];
  const float* Wf1 = (const float*)d_in[21];
  const float* bf1 = (const float*)d_in[22];
  const float* Wf2 = (const float*)d_in[23];
  const float* bf2 = (const float*)d_in[24];
  const float* lnfg = (const float*)d_in[25];
  const float* lnfb = (const float*)d_in[26];
  const float* pool_w = (const float*)d_in[27];
  const float* pj_g1 = (const float*)d_in[28];
  const float* pj_b1 = (const float*)d_in[29];
  const float* pj_W1 = (const float*)d_in[30];
  const float* pj_c1 = (const float*)d_in[31];
  const float* pj_g2 = (const float*)d_in[32];
  const float* pj_b2 = (const float*)d_in[33];
  const float* pj_W2 = (const float*)d_in[34];
  const float* pj_c2 = (const float*)d_in[35];
  float* out = (float*)d_out;

  // ---- workspace layout (~141 MB). doc rows [0,4096), sum rows [4096,6144). ----
  const size_t n_x = (size_t)MTOT * HD;  // 4,718,592
  float* x      = (float*)d_ws;
  float* cbuf   = x + n_x;
  float* pooled = cbuf + n_x;                    // 64*768
  float* g1     = pooled + 2 * NSPAN * HD;
  float* h2     = g1 + 2 * NSPAN * HD;
  float* proj   = h2 + 2 * NSPAN * HD;           // 64*256
  float* dots   = proj + 2 * NSPAN * PD;         // 6144
  float* probs  = dots + MTOT;                   // 64*2048
  float* pbuf   = probs + 2 * NSPAN * SDOC;      // KSPLIT*64*768 split-K partials
  unsigned short* xbf    = (unsigned short*)(pbuf + (size_t)KSPLIT * 2 * NSPAN * HD);
  unsigned short* qkv_bf = xbf + n_x;                          // MTOT*2304
  unsigned short* ab_bf  = qkv_bf + (size_t)MTOT * QKVN;       // MTOT*768
  unsigned short* h_bf   = ab_bf + n_x;                        // MTOT*3072
  unsigned short* wt_bf  = h_bf + (size_t)MTOT * FFD;          // 7,077,888

  embed_ln_kernel<<<BB * SDOC, 256, 0, stream>>>(doc_ids, word_emb, pos_emb, emb_g, emb_b,
                                                 x, xbf, SDOC);
  embed_ln_kernel<<<BB * SSUM, 256, 0, stream>>>(sum_ids, word_emb, pos_emb, emb_g, emb_b,
                                                 x + (size_t)BB * SDOC * HD,
                                                 xbf + (size_t)BB * SDOC * HD, SSUM);

  const size_t sum_off = (size_t)BB * SDOC;  // row offset of sum region
  for (int l = 0; l < NLAYER; l++) {
    tc_cast_kernel<<<dim3(2304, 1, 6), 256, 0, stream>>>(
        Wq + (size_t)l * HD * HD, Wk + (size_t)l * HD * HD, Wv + (size_t)l * HD * HD,
        Wo + (size_t)l * HD * HD, Wf1 + (size_t)l * HD * FFD, Wf2 + (size_t)l * FFD * HD,
        wt_bf);
    // fused QKV over merged rows -> bf16
    launch_gemm128(xbf, wt_bf + WOFF_QKV, bq + l * HD, bk + l * HD, bv + l * HD, HD,
                   nullptr, qkv_bf, MTOT, QKVN, HD, 0, stream);
    attn_mfma<<<dim3(SDOC / AQT, NHEAD, BB), 256, 0, stream>>>(qkv_bf, doc_am, ab_bf, SDOC);
    attn_mfma<<<dim3(SSUM / AQT, NHEAD, BB), 256, 0, stream>>>(
        qkv_bf + sum_off * QKVN, sum_am, ab_bf + sum_off * HD, SSUM);
    // O-proj -> fp32 (TN=128: 16 MFMA per 8 ds_read_b128 per K-step vs 8:6 at TN=64)
    launch_gemm128(ab_bf, wt_bf + WOFF_O, bo + l * HD, bo + l * HD, bo + l * HD, HD,
                   cbuf, nullptr, MTOT, HD, HD, 0, stream);
    ln_kernel<<<MTOT, 256, 0, stream>>>(cbuf, x, lnag + l * HD, lnab + l * HD, x, xbf);
    // FFN1 + GELU -> bf16
    launch_gemm128(xbf, wt_bf + WOFF_F1, bf1 + l * FFD, bf1 + l * FFD, bf1 + l * FFD, FFD,
                   nullptr, h_bf, MTOT, FFD, HD, 1, stream);
    // FFN2 -> fp32 (TN=128)
    launch_gemm128(h_bf, wt_bf + WOFF_F2, bf2 + l * HD, bf2 + l * HD, bf2 + l * HD, HD,
                   cbuf, nullptr, MTOT, HD, FFD, 0, stream);
    ln_kernel<<<MTOT, 256, 0, stream>>>(cbuf, x, lnfg + l * HD, lnfb + l * HD, x, xbf);
  }

  // ---- pooling + projection head (both passes merged; ns 0..31 = human, 32..63 = llm) ----
  dots_kernel<<<MTOT / 4, 256, 0, stream>>>(x, pool_w, dots);
  span_softmax_kernel<<<2 * NSPAN, 256, 0, stream>>>(dots, og_spans, llm_spans, sidx, probs);
  hipMemsetAsync(pooled, 0, 2 * NSPAN * HD * sizeof(float), stream);
  wsum_kernel<<<dim3(SDOC / 256, NSPAN), 256, 0, stream>>>(x, probs, sidx, pooled, SDOC, 0);
  wsum_kernel<<<dim3(SSUM / 256, NSPAN), 256, 0, stream>>>(
      x + sum_off * HD, probs, sidx, pooled, SSUM, NSPAN);
  ln_kernel<<<2 * NSPAN, 256, 0, stream>>>(pooled, nullptr, pj_g1, pj_b1, h2, nullptr);
  gemm_ps_kernel<<<dim3(HD / 256, 2 * NSPAN, KSPLIT), 256, 0, stream>>>(h2, pj_W1, pbuf, HD, HD);
  gemm_reduce_kernel<<<dim3(HD / 256, 2 * NSPAN), 256, 0, stream>>>(pbuf, pj_c1, g1, HD, 1);
  ln_kernel<<<2 * NSPAN, 256, 0, stream>>>(g1, nullptr, pj_g2, pj_b2, h2, nullptr);
  gemm_ps_kernel<<<dim3(PD / 256, 2 * NSPAN, KSPLIT), 256, 0, stream>>>(h2, pj_W2, pbuf, PD, HD);
  gemm_reduce_kernel<<<dim3(PD / 256, 2 * NSPAN), 256, 0, stream>>>(pbuf, pj_c2, proj, PD, 0);
  norm_out_kernel<<<2 * NSPAN, 256, 0, stream>>>(proj, out);
}

// Round 3
// 2488.719 us; speedup vs baseline: 1.0443x; 1.0049x over previous
//
#include <hip/hip_runtime.h>
#include <math.h>

#define BB 2
#define SDOC 2048
#define SSUM 1024
#define HD 768
#define NHEAD 12
#define DHEAD 64
#define FFD 3072
#define NLAYER 6
#define PD 256
#define NSPAN 32
#define WINSZ 256
#define QKVN 2304   // fused QKV output width
#define MTOT 6144   // merged rows: BB*SDOC + BB*SSUM
#define KSPLIT 16   // split-K factor for the tiny projection-head GEMMs

typedef short s16x8 __attribute__((ext_vector_type(8)));
typedef float f32x4 __attribute__((ext_vector_type(4)));

#define LDS_PTR(p) ((__attribute__((address_space(3))) void*)(p))
#define GLB_PTR(p) ((const __attribute__((address_space(1))) void*)(p))

// ---------------- bf16 helpers (RNE) ----------------
__device__ __forceinline__ unsigned short f2bf(float f) {
  unsigned int u = __builtin_bit_cast(unsigned int, f);
  unsigned int r = (u + 0x7fffu + ((u >> 16) & 1u)) >> 16;
  return (unsigned short)r;
}
__device__ __forceinline__ float bf2f(unsigned short h) {
  unsigned int u = ((unsigned int)h) << 16;
  return __builtin_bit_cast(float, u);
}

// fast GELU (tanh form via exp). max abs err ~2e-4 — far below bf16 noise.
__device__ __forceinline__ float gelu_f(float x) {
  float t = x * (0.7978845608f + 0.0356774081f * x * x);
  float e = __expf(2.f * t);
  float th = 1.f - 2.f / (e + 1.f);
  return 0.5f * x * (1.f + th);
}

// ---------------- reductions (blockDim == 256): wave shuffle + 1 LDS combine ----------------
// Old LDS-tree had 8 __syncthreads per call (16/row for LN). These use 2.
__device__ __forceinline__ float wave_reduce_sum(float v) {
#pragma unroll
  for (int m = 32; m > 0; m >>= 1) v += __shfl_xor(v, m, 64);
  return v;
}
__device__ __forceinline__ float wave_reduce_max(float v) {
#pragma unroll
  for (int m = 32; m > 0; m >>= 1) v = fmaxf(v, __shfl_xor(v, m, 64));
  return v;
}

__device__ __forceinline__ float block_reduce_sum(float v) {
  __shared__ float s[4];
  v = wave_reduce_sum(v);
  int wave = threadIdx.x >> 6;
  if ((threadIdx.x & 63) == 0) s[wave] = v;
  __syncthreads();
  float r = (s[0] + s[1]) + (s[2] + s[3]);
  __syncthreads();  // safe reuse across sequential calls
  return r;
}

__device__ __forceinline__ float block_reduce_max(float v) {
  __shared__ float s[4];
  v = wave_reduce_max(v);
  int wave = threadIdx.x >> 6;
  if ((threadIdx.x & 63) == 0) s[wave] = v;
  __syncthreads();
  float r = fmaxf(fmaxf(s[0], s[1]), fmaxf(s[2], s[3]));
  __syncthreads();
  return r;
}

// fused two-value sum reduce (mean + sumsq in ONE pass for LayerNorm)
__device__ __forceinline__ void block_reduce_sum2(float& a, float& b) {
  __shared__ float sa[4], sb[4];
#pragma unroll
  for (int m = 32; m > 0; m >>= 1) {
    a += __shfl_xor(a, m, 64);
    b += __shfl_xor(b, m, 64);
  }
  int wave = threadIdx.x >> 6;
  if ((threadIdx.x & 63) == 0) { sa[wave] = a; sb[wave] = b; }
  __syncthreads();
  a = (sa[0] + sa[1]) + (sa[2] + sa[3]);
  b = (sb[0] + sb[1]) + (sb[2] + sb[3]);
  __syncthreads();
}

// ---------------- embedding + LayerNorm + bf16 ----------------
__global__ __launch_bounds__(256) void embed_ln_kernel(
    const int* __restrict__ ids, const float* __restrict__ we, const float* __restrict__ pe,
    const float* __restrict__ g, const float* __restrict__ bt, float* __restrict__ xout,
    unsigned short* __restrict__ xb, int S) {
  int row = blockIdx.x;
  int s = row % S;
  int id = ids[row];
  int tid = threadIdx.x;
  float vals[3];
  float sum = 0.f, sq = 0.f;
#pragma unroll
  for (int i = 0; i < 3; i++) {
    int h = tid + i * 256;
    float t = we[(size_t)id * HD + h] + pe[(size_t)s * HD + h];
    vals[i] = t;
    sum += t;
    sq += t * t;
  }
  block_reduce_sum2(sum, sq);
  float mean = sum * (1.f / HD);
  float var = fmaxf(sq * (1.f / HD) - mean * mean, 0.f);
  float inv = rsqrtf(var + 1e-5f);
#pragma unroll
  for (int i = 0; i < 3; i++) {
    int h = tid + i * 256;
    float v = (vals[i] - mean) * inv * g[h] + bt[h];
    size_t off = (size_t)row * HD + h;
    xout[off] = v;
    xb[off] = f2bf(v);
  }
}

// ---------------- LayerNorm (+optional residual, +optional bf16 out) ----------------
__global__ __launch_bounds__(256) void ln_kernel(
    const float* __restrict__ a, const float* __restrict__ res,
    const float* __restrict__ g, const float* __restrict__ bt, float* __restrict__ out,
    unsigned short* __restrict__ ob) {
  int row = blockIdx.x;
  int tid = threadIdx.x;
  const float* ar = a + (size_t)row * HD;
  const float* rr = res ? res + (size_t)row * HD : nullptr;
  float vals[3];
  float sum = 0.f, sq = 0.f;
#pragma unroll
  for (int i = 0; i < 3; i++) {
    int h = tid + i * 256;
    float t = ar[h] + (rr ? rr[h] : 0.f);
    vals[i] = t;
    sum += t;
    sq += t * t;
  }
  block_reduce_sum2(sum, sq);
  float mean = sum * (1.f / HD);
  float var = fmaxf(sq * (1.f / HD) - mean * mean, 0.f);
  float inv = rsqrtf(var + 1e-5f);
#pragma unroll
  for (int i = 0; i < 3; i++) {
    int h = tid + i * 256;
    float v = (vals[i] - mean) * inv * g[h] + bt[h];
    size_t off = (size_t)row * HD + h;
    out[off] = v;
    if (ob) ob[off] = f2bf(v);
  }
}

// ---------------- per-layer weight transpose + bf16 cast ----------------
__global__ __launch_bounds__(256) void tc_cast_kernel(
    const float* __restrict__ Wq, const float* __restrict__ Wk, const float* __restrict__ Wv,
    const float* __restrict__ Wo, const float* __restrict__ Wf1, const float* __restrict__ Wf2,
    unsigned short* __restrict__ ob) {
  __shared__ float tile[32][33];
  int z = blockIdx.z;
  const float* W;
  int Kd, Nd;
  size_t off;
  switch (z) {
    case 0: W = Wq;  Kd = HD;  Nd = HD;  off = 0;        break;
    case 1: W = Wk;  Kd = HD;  Nd = HD;  off = 589824;   break;
    case 2: W = Wv;  Kd = HD;  Nd = HD;  off = 1179648;  break;
    case 3: W = Wo;  Kd = HD;  Nd = HD;  off = 1769472;  break;
    case 4: W = Wf1; Kd = HD;  Nd = FFD; off = 2359296;  break;
    default: W = Wf2; Kd = FFD; Nd = HD; off = 4718592;  break;
  }
  int tiles_n = Nd >> 5, tiles_k = Kd >> 5;
  int t = blockIdx.x;
  if (t >= tiles_n * tiles_k) return;
  int tn = t % tiles_n, tk = t / tiles_n;
  int n0 = tn * 32, k0 = tk * 32;
  int tid = threadIdx.x;
  int c = tid & 31, r0 = tid >> 5;
#pragma unroll
  for (int j = 0; j < 4; j++) {
    int r = r0 + j * 8;
    tile[r][c] = W[(size_t)(k0 + r) * Nd + n0 + c];
  }
  __syncthreads();
#pragma unroll
  for (int j = 0; j < 4; j++) {
    int r = r0 + j * 8;  // r = local n, c = local k
    ob[off + (size_t)(n0 + r) * Kd + k0 + c] = f2bf(tile[c][r]);
  }
}

// ---------------- bf16 MFMA GEMM, double-buffered LDS, templated N-tile ----------------
// C(M,N) = A(M,K)bf16 @ B^T, B stored (N,K) row-major bf16. Block tile 128 x TN.
// bias segments: col c -> bias[c/seg] ptr b0/b1/b2, offset c%seg.
// act=1: fast GELU. Output fp32 C (if non-null) and/or bf16 Oh (if non-null).
template <int TN>
__global__ __launch_bounds__(256) void gemm_mfma_t(
    const unsigned short* __restrict__ A, const unsigned short* __restrict__ B,
    const float* __restrict__ b0, const float* __restrict__ b1, const float* __restrict__ b2,
    int seg, float* __restrict__ C, unsigned short* __restrict__ Oh,
    int M, int N, int K, int act) {
  constexpr int JT = TN / 32;  // n-fragments per wave
  __shared__ __align__(16) unsigned short sA[2][128 * 32];
  __shared__ __align__(16) unsigned short sB[2][TN * 32];
  int tid = threadIdx.x;
  int bm = blockIdx.y * 128, bn = blockIdx.x * TN;
  int wave = tid >> 6, lane = tid & 63;
  int quad = lane >> 4, l16 = lane & 15;
  int wm = (wave >> 1) * 64, wn = (wave & 1) * (TN / 2);

  f32x4 zero = {0.f, 0.f, 0.f, 0.f};
  f32x4 acc[4][JT];
#pragma unroll
  for (int i = 0; i < 4; i++)
#pragma unroll
    for (int j = 0; j < JT; j++) acc[i][j] = zero;

  int e0 = tid * 8;
  int row0 = e0 >> 5;
  int kk0 = e0 & 31;

  auto issue = [&](int kb, int buf) {
    int k0 = kb * 32;
#pragma unroll
    for (int r = 0; r < 2; r++) {
      int row = row0 + r * 64;
      int le = (r * 256 + tid) * 8;
      size_t ga = (size_t)(bm + row) * K + k0 + kk0;
      __builtin_amdgcn_global_load_lds(GLB_PTR(A + ga), LDS_PTR(&sA[buf][le]), 16, 0, 0);
    }
#pragma unroll
    for (int r = 0; r < TN / 64; r++) {
      int row = row0 + r * 64;
      int le = (r * 256 + tid) * 8;
      size_t gb = (size_t)(bn + row) * K + k0 + kk0;
      __builtin_amdgcn_global_load_lds(GLB_PTR(B + gb), LDS_PTR(&sB[buf][le]), 16, 0, 0);
    }
  };

  int nk = K >> 5;
  issue(0, 0);
  for (int kb = 0; kb < nk; kb++) {
    __syncthreads();  // drains loads for buf kb&1; ensures prior reads of other buf done
    if (kb + 1 < nk) issue(kb + 1, (kb + 1) & 1);
    int buf = kb & 1;
    s16x8 af[4], bf[JT];
#pragma unroll
    for (int i = 0; i < 4; i++)
      af[i] = *(const s16x8*)&sA[buf][(wm + i * 16 + l16) * 32 + quad * 8];
#pragma unroll
    for (int j = 0; j < JT; j++)
      bf[j] = *(const s16x8*)&sB[buf][(wn + j * 16 + l16) * 32 + quad * 8];
#pragma unroll
    for (int i = 0; i < 4; i++)
#pragma unroll
      for (int j = 0; j < JT; j++)
        acc[i][j] = __builtin_amdgcn_mfma_f32_16x16x32_bf16(af[i], bf[j], acc[i][j], 0, 0, 0);
  }

#pragma unroll
  for (int j = 0; j < JT; j++) {
    int col = bn + wn + j * 16 + l16;
    int bidx = col / seg;
    int boff = col - bidx * seg;
    const float* bp = bidx == 0 ? b0 : (bidx == 1 ? b1 : b2);
    float bv = bp[boff];
#pragma unroll
    for (int i = 0; i < 4; i++) {
#pragma unroll
      for (int r = 0; r < 4; r++) {
        int rowg = bm + wm + i * 16 + quad * 4 + r;
        float v = acc[i][j][r] + bv;
        if (act == 1) v = gelu_f(v);
        size_t off = (size_t)rowg * N + col;
        if (C) C[off] = v;
        if (Oh) Oh[off] = f2bf(v);
      }
    }
  }
}

// ---------------- projection-head GEMM: split-K partials + fused reduce ----------------
__global__ __launch_bounds__(256) void gemm_ps_kernel(
    const float* __restrict__ A, const float* __restrict__ W,
    float* __restrict__ part, int N, int K) {
  int n = blockIdx.x * 256 + threadIdx.x;
  int m = blockIdx.y;
  int M = gridDim.y;
  int ks = blockIdx.z;
  int kc = K / KSPLIT;
  int k0 = ks * kc;
  const float* ar = A + (size_t)m * K + k0;
  const float* wr = W + (size_t)k0 * N + n;
  float a0 = 0.f, a1 = 0.f, a2 = 0.f, a3 = 0.f;
  for (int k = 0; k < kc; k += 4) {
    a0 += ar[k]     * wr[(size_t)k * N];
    a1 += ar[k + 1] * wr[(size_t)(k + 1) * N];
    a2 += ar[k + 2] * wr[(size_t)(k + 2) * N];
    a3 += ar[k + 3] * wr[(size_t)(k + 3) * N];
  }
  part[((size_t)ks * M + m) * N + n] = (a0 + a1) + (a2 + a3);
}

__global__ __launch_bounds__(256) void gemm_reduce_kernel(
    const float* __restrict__ part, const float* __restrict__ bias,
    float* __restrict__ C, int N, int act) {
  int n = blockIdx.x * 256 + threadIdx.x;
  int m = blockIdx.y;
  int M = gridDim.y;
  float s = 0.f;
#pragma unroll
  for (int ks = 0; ks < KSPLIT; ks++) s += part[((size_t)ks * M + m) * N + n];
  s += bias[n];
  if (act == 1) s = gelu_f(s);
  C[(size_t)m * N + n] = s;
}

// ---------------- MFMA sliding-window attention ----------------
#define AQT 64
__global__ __launch_bounds__(256) void attn_mfma(
    const unsigned short* __restrict__ qkv, const int* __restrict__ amask,
    unsigned short* __restrict__ Oh, int S) {
  __shared__ unsigned short Vs[64][72];      // V^T: [d][key], +8 pad
  __shared__ unsigned short Ps[4][16][72];   // per-wave P (query, key), +8 pad
  int b = blockIdx.z, hd = blockIdx.y;
  int p0 = blockIdx.x * AQT;
  int tid = threadIdx.x;
  int wave = tid >> 6, lane = tid & 63;
  int quad = lane >> 4, l16 = lane & 15;
  int kstart = p0 - WINSZ;
  const unsigned short* base = qkv + (size_t)(b * S) * QKVN + hd * DHEAD;

  s16x8 aq[2];
  {
    const unsigned short* qrow = base + (size_t)(p0 + wave * 16 + l16) * QKVN;
    aq[0] = *(const s16x8*)(qrow + quad * 8);
    aq[1] = *(const s16x8*)(qrow + 32 + quad * 8);
  }
  f32x4 o[4];
  f32x4 zero = {0.f, 0.f, 0.f, 0.f};
#pragma unroll
  for (int i = 0; i < 4; i++) o[i] = zero;
  float mi[4] = {-1e30f, -1e30f, -1e30f, -1e30f};
  float li[4] = {0.f, 0.f, 0.f, 0.f};

  for (int t = 0; t < 9; t++) {
    __syncthreads();
    {
      int key = tid & 63, d0 = (tid >> 6) * 16;
      int kp = kstart + t * 64 + key;
      if (kp >= 0 && kp < S) {
        const unsigned short* vrow = base + (size_t)kp * QKVN + 2 * HD + d0;
        s16x8 v0 = *(const s16x8*)(vrow);
        s16x8 v1 = *(const s16x8*)(vrow + 8);
#pragma unroll
        for (int j = 0; j < 8; j++) Vs[d0 + j][key] = (unsigned short)v0[j];
#pragma unroll
        for (int j = 0; j < 8; j++) Vs[d0 + 8 + j][key] = (unsigned short)v1[j];
      } else {
#pragma unroll
        for (int j = 0; j < 16; j++) Vs[d0 + j][key] = 0;
      }
    }
    __syncthreads();

    f32x4 sc[4];
#pragma unroll
    for (int nt = 0; nt < 4; nt++) {
      int kr = kstart + t * 64 + nt * 16 + l16;
      s16x8 bk0 = {0, 0, 0, 0, 0, 0, 0, 0}, bk1 = bk0;
      if (kr >= 0 && kr < S) {
        const unsigned short* krow = base + (size_t)kr * QKVN + HD;
        bk0 = *(const s16x8*)(krow + quad * 8);
        bk1 = *(const s16x8*)(krow + 32 + quad * 8);
      }
      sc[nt] = __builtin_amdgcn_mfma_f32_16x16x32_bf16(aq[0], bk0, zero, 0, 0, 0);
      sc[nt] = __builtin_amdgcn_mfma_f32_16x16x32_bf16(aq[1], bk1, sc[nt], 0, 0, 0);
    }

    float s_val[4][4];
    float tm[4] = {-1e30f, -1e30f, -1e30f, -1e30f};
#pragma unroll
    for (int nt = 0; nt < 4; nt++) {
      int j = t * 64 + nt * 16 + l16;
      int kp = kstart + j;
      int am = (kp >= 0 && kp < S) ? amask[b * S + kp] : 0;
#pragma unroll
      for (int r = 0; r < 4; r++) {
        int ql = wave * 16 + quad * 4 + r;
        bool valid = (am != 0) && (j >= ql) && (j <= ql + 512);
        float v = valid ? sc[nt][r] * 0.125f : -1e9f;
        s_val[nt][r] = v;
        tm[r] = fmaxf(tm[r], v);
      }
    }
#pragma unroll
    for (int m = 1; m < 16; m <<= 1)
#pragma unroll
      for (int r = 0; r < 4; r++) tm[r] = fmaxf(tm[r], __shfl_xor(tm[r], m, 16));

    float alpha[4], rs[4];
#pragma unroll
    for (int r = 0; r < 4; r++) {
      float mn = fmaxf(mi[r], tm[r]);
      alpha[r] = __expf(mi[r] - mn);
      mi[r] = mn;
      rs[r] = 0.f;
    }
#pragma unroll
    for (int nt = 0; nt < 4; nt++)
#pragma unroll
      for (int r = 0; r < 4; r++) {
        float p = __expf(s_val[nt][r] - mi[r]);
        rs[r] += p;
        Ps[wave][quad * 4 + r][nt * 16 + l16] = f2bf(p);
      }
#pragma unroll
    for (int m = 1; m < 16; m <<= 1)
#pragma unroll
      for (int r = 0; r < 4; r++) rs[r] += __shfl_xor(rs[r], m, 16);
#pragma unroll
    for (int r = 0; r < 4; r++) li[r] = li[r] * alpha[r] + rs[r];
#pragma unroll
    for (int dn = 0; dn < 4; dn++)
#pragma unroll
      for (int r = 0; r < 4; r++) o[dn][r] *= alpha[r];

#pragma unroll
    for (int ks = 0; ks < 2; ks++) {
      s16x8 ap = *(const s16x8*)&Ps[wave][l16][ks * 32 + quad * 8];
#pragma unroll
      for (int dn = 0; dn < 4; dn++) {
        s16x8 bv = *(const s16x8*)&Vs[dn * 16 + l16][ks * 32 + quad * 8];
        o[dn] = __builtin_amdgcn_mfma_f32_16x16x32_bf16(ap, bv, o[dn], 0, 0, 0);
      }
    }
  }

#pragma unroll
  for (int r = 0; r < 4; r++) {
    float inv = 1.f / li[r];
    int rowg = b * S + p0 + wave * 16 + quad * 4 + r;
#pragma unroll
    for (int dn = 0; dn < 4; dn++) {
      Oh[(size_t)rowg * HD + hd * DHEAD + dn * 16 + l16] = f2bf(o[dn][r] * inv);
    }
  }
}

// ---------------- pooling path ----------------
__global__ __launch_bounds__(256) void dots_kernel(
    const float* __restrict__ x, const float* __restrict__ pw, float* __restrict__ dots) {
  int row = blockIdx.x * 4 + (threadIdx.x >> 6);
  int lane = threadIdx.x & 63;
  const float* r = x + (size_t)row * HD;
  float s = 0.f;
  for (int i = lane; i < HD; i += 64) s += r[i] * pw[i];
#pragma unroll
  for (int m = 32; m > 0; m >>= 1) s += __shfl_xor(s, m, 64);
  if (lane == 0) dots[row] = fminf(fmaxf(s, -100.f), 100.f);
}

// merged masked softmax: blocks 0..31 = og spans (doc), 32..63 = llm spans (sum)
__global__ __launch_bounds__(256) void span_softmax_kernel(
    const float* __restrict__ dots, const int* __restrict__ og_spans,
    const int* __restrict__ llm_spans, const int* __restrict__ sidx,
    float* __restrict__ probs) {
  int ns = blockIdx.x;
  int pass = ns >> 5;
  int sp = ns & 31;
  int S = pass ? SSUM : SDOC;
  const int* spans = pass ? llm_spans : og_spans;
  int rowbase = pass ? BB * SDOC : 0;
  int bi = sidx[sp];
  const float* dr = dots + rowbase + bi * S;
  int tid = threadIdx.x;
  float mx = -1e30f;
  for (int s = tid; s < S; s += 256) {
    float v = (spans[sp * S + s] == 1) ? dr[s] : -1e9f;
    mx = fmaxf(mx, v);
  }
  mx = block_reduce_max(mx);
  float sum = 0.f;
  for (int s = tid; s < S; s += 256) {
    float v = (spans[sp * S + s] == 1) ? dr[s] : -1e9f;
    float e = __expf(v - mx);
    probs[ns * SDOC + s] = e;
    sum += e;
  }
  sum = block_reduce_sum(sum);
  float inv = 1.f / sum;
  for (int s = tid; s < S; s += 256) probs[ns * SDOC + s] *= inv;
}

// pooled[ns][h] += sum_{s in chunk} probs[ns][s] * seq[bi][s][h]
__global__ __launch_bounds__(256) void wsum_kernel(
    const float* __restrict__ seq, const float* __restrict__ probs,
    const int* __restrict__ sidx, float* __restrict__ pooled, int S, int ns0) {
  __shared__ float ps[256];
  int sp = blockIdx.y;
  int ns = ns0 + sp;
  int s0 = blockIdx.x * 256;
  int bi = sidx[sp];
  int tid = threadIdx.x;
  ps[tid] = probs[ns * SDOC + s0 + tid];
  __syncthreads();
  const float* xb = seq + ((size_t)bi * S + s0) * HD;
  float a0 = 0.f, a1 = 0.f, a2 = 0.f;
  for (int s = 0; s < 256; s++) {
    float p = ps[s];
    const float* row = xb + (size_t)s * HD;
    a0 += p * row[tid];
    a1 += p * row[tid + 256];
    a2 += p * row[tid + 512];
  }
  atomicAdd(&pooled[ns * HD + tid], a0);
  atomicAdd(&pooled[ns * HD + tid + 256], a1);
  atomicAdd(&pooled[ns * HD + tid + 512], a2);
}

// ---------------- final L2 normalize ----------------
__global__ __launch_bounds__(256) void norm_out_kernel(
    const float* __restrict__ proj, float* __restrict__ out) {
  int ns = blockIdx.x;
  float v = proj[ns * PD + threadIdx.x];
  float ss = block_reduce_sum(v * v);
  float n = fmaxf(sqrtf(ss), 1e-12f);
  out[ns * PD + threadIdx.x] = v / n;
}

// ---------------- host side ----------------
static void launch_gemm128(const unsigned short* A, const unsigned short* B,
                           const float* b0, const float* b1, const float* b2, int seg,
                           float* C, unsigned short* Oh, int M, int N, int K, int act,
                           hipStream_t stream) {
  dim3 grid(N / 128, M / 128);
  gemm_mfma_t<128><<<grid, 256, 0, stream>>>(A, B, b0, b1, b2, seg, C, Oh, M, N, K, act);
}

// weight segment offsets in the per-layer transposed cache (elements)
#define WOFF_QKV 0
#define WOFF_O   1769472
#define WOFF_F1  2359296
#define WOFF_F2  4718592

extern "C" void kernel_launch(void* const* d_in, const int* in_sizes, int n_in,
                              void* d_out, int out_size, void* d_ws, size_t ws_size,
                              hipStream_t stream) {
  const int* doc_ids   = (const int*)d_in[0];
  const int* doc_am    = (const int*)d_in[1];
  const int* sum_ids   = (const int*)d_in[2];
  const int* sum_am    = (const int*)d_in[3];
  const int* og_spans  = (const int*)d_in[4];
  const int* llm_spans = (const int*)d_in[5];
  const int* sidx      = (const int*)d_in[6];
  const float* word_emb = (const float*)d_in[7];
  const float* pos_emb  = (const float*)d_in[8];
  const float* emb_g = (const float*)d_in[9];
  const float* emb_b = (const float*)d_in[10];
  const float* Wq = (const float*)d_in[11];
  const float* bq = (const float*)d_in[12];
  const float* Wk = (const float*)d_in[13];
  const float* bk = (const float*)d_in[14];
  const float* Wv = (const float*)d_in[15];
  const float* bv = (const float*)d_in[16];
  const float* Wo = (const float*)d_in[17];
  const float* bo = (const float*)d_in[18];
  const float* lnag = (const float*)d_in[19];
  const float* lnab = (const float*)d_in[20];
  const float* Wf1 = (const float*)d_in[21];
  const float* bf1 = (const float*)d_in[22];
  const float* Wf2 = (const float*)d_in[23];
  const float* bf2 = (const float*)d_in[24];
  const float* lnfg = (const float*)d_in[25];
  const float* lnfb = (const float*)d_in[26];
  const float* pool_w = (const float*)d_in[27];
  const float* pj_g1 = (const float*)d_in[28];
  const float* pj_b1 = (const float*)d_in[29];
  const float* pj_W1 = (const float*)d_in[30];
  const float* pj_c1 = (const float*)d_in[31];
  const float* pj_g2 = (const float*)d_in[32];
  const float* pj_b2 = (const float*)d_in[33];
  const float* pj_W2 = (const float*)d_in[34];
  const float* pj_c2 = (const float*)d_in[35];
  float* out = (float*)d_out;

  // ---- workspace layout (~141 MB). doc rows [0,4096), sum rows [4096,6144). ----
  const size_t n_x = (size_t)MTOT * HD;  // 4,718,592
  float* x      = (float*)d_ws;
  float* cbuf   = x + n_x;
  float* pooled = cbuf + n_x;                    // 64*768
  float* g1     = pooled + 2 * NSPAN * HD;
  float* h2     = g1 + 2 * NSPAN * HD;
  float* proj   = h2 + 2 * NSPAN * HD;           // 64*256
  float* dots   = proj + 2 * NSPAN * PD;         // 6144
  float* probs  = dots + MTOT;                   // 64*2048
  float* pbuf   = probs + 2 * NSPAN * SDOC;      // KSPLIT*64*768 split-K partials
  unsigned short* xbf    = (unsigned short*)(pbuf + (size_t)KSPLIT * 2 * NSPAN * HD);
  unsigned short* qkv_bf = xbf + n_x;                          // MTOT*2304
  unsigned short* ab_bf  = qkv_bf + (size_t)MTOT * QKVN;       // MTOT*768
  unsigned short* h_bf   = ab_bf + n_x;                        // MTOT*3072
  unsigned short* wt_bf  = h_bf + (size_t)MTOT * FFD;          // 7,077,888

  embed_ln_kernel<<<BB * SDOC, 256, 0, stream>>>(doc_ids, word_emb, pos_emb, emb_g, emb_b,
                                                 x, xbf, SDOC);
  embed_ln_kernel<<<BB * SSUM, 256, 0, stream>>>(sum_ids, word_emb, pos_emb, emb_g, emb_b,
                                                 x + (size_t)BB * SDOC * HD,
                                                 xbf + (size_t)BB * SDOC * HD, SSUM);

  const size_t sum_off = (size_t)BB * SDOC;  // row offset of sum region
  for (int l = 0; l < NLAYER; l++) {
    tc_cast_kernel<<<dim3(2304, 1, 6), 256, 0, stream>>>(
        Wq + (size_t)l * HD * HD, Wk + (size_t)l * HD * HD, Wv + (size_t)l * HD * HD,
        Wo + (size_t)l * HD * HD, Wf1 + (size_t)l * HD * FFD, Wf2 + (size_t)l * FFD * HD,
        wt_bf);
    // fused QKV over merged rows -> bf16
    launch_gemm128(xbf, wt_bf + WOFF_QKV, bq + l * HD, bk + l * HD, bv + l * HD, HD,
                   nullptr, qkv_bf, MTOT, QKVN, HD, 0, stream);
    attn_mfma<<<dim3(SDOC / AQT, NHEAD, BB), 256, 0, stream>>>(qkv_bf, doc_am, ab_bf, SDOC);
    attn_mfma<<<dim3(SSUM / AQT, NHEAD, BB), 256, 0, stream>>>(
        qkv_bf + sum_off * QKVN, sum_am, ab_bf + sum_off * HD, SSUM);
    // O-proj -> fp32 (TN=128)
    launch_gemm128(ab_bf, wt_bf + WOFF_O, bo + l * HD, bo + l * HD, bo + l * HD, HD,
                   cbuf, nullptr, MTOT, HD, HD, 0, stream);
    ln_kernel<<<MTOT, 256, 0, stream>>>(cbuf, x, lnag + l * HD, lnab + l * HD, x, xbf);
    // FFN1 + GELU -> bf16
    launch_gemm128(xbf, wt_bf + WOFF_F1, bf1 + l * FFD, bf1 + l * FFD, bf1 + l * FFD, FFD,
                   nullptr, h_bf, MTOT, FFD, HD, 1, stream);
    // FFN2 -> fp32 (TN=128)
    launch_gemm128(h_bf, wt_bf + WOFF_F2, bf2 + l * HD, bf2 + l * HD, bf2 + l * HD, HD,
                   cbuf, nullptr, MTOT, HD, FFD, 0, stream);
    ln_kernel<<<MTOT, 256, 0, stream>>>(cbuf, x, lnfg + l * HD, lnfb + l * HD, x, xbf);
  }

  // ---- pooling + projection head (both passes merged; ns 0..31 = human, 32..63 = llm) ----
  dots_kernel<<<MTOT / 4, 256, 0, stream>>>(x, pool_w, dots);
  span_softmax_kernel<<<2 * NSPAN, 256, 0, stream>>>(dots, og_spans, llm_spans, sidx, probs);
  hipMemsetAsync(pooled, 0, 2 * NSPAN * HD * sizeof(float), stream);
  wsum_kernel<<<dim3(SDOC / 256, NSPAN), 256, 0, stream>>>(x, probs, sidx, pooled, SDOC, 0);
  wsum_kernel<<<dim3(SSUM / 256, NSPAN), 256, 0, stream>>>(
      x + sum_off * HD, probs, sidx, pooled, SSUM, NSPAN);
  ln_kernel<<<2 * NSPAN, 256, 0, stream>>>(pooled, nullptr, pj_g1, pj_b1, h2, nullptr);
  gemm_ps_kernel<<<dim3(HD / 256, 2 * NSPAN, KSPLIT), 256, 0, stream>>>(h2, pj_W1, pbuf, HD, HD);
  gemm_reduce_kernel<<<dim3(HD / 256, 2 * NSPAN), 256, 0, stream>>>(pbuf, pj_c1, g1, HD, 1);
  ln_kernel<<<2 * NSPAN, 256, 0, stream>>>(g1, nullptr, pj_g2, pj_b2, h2, nullptr);
  gemm_ps_kernel<<<dim3(PD / 256, 2 * NSPAN, KSPLIT), 256, 0, stream>>>(h2, pj_W2, pbuf, PD, HD);
  gemm_reduce_kernel<<<dim3(PD / 256, 2 * NSPAN), 256, 0, stream>>>(pbuf, pj_c2, proj, PD, 0);
  norm_out_kernel<<<2 * NSPAN, 256, 0, stream>>>(proj, out);
}